// Round 1
// baseline (891.946 us; speedup 1.0000x reference)
//
#include <hip/hip_runtime.h>
#include <math.h>

#define NLEV 16
#define TBL  (1u << 19)
#define TMASK (TBL - 1u)

struct ResParams { float resf[NLEV]; };

__device__ __forceinline__ float sigmoidf(float x) {
    return 1.0f / (1.0f + __expf(-x));
}

// ---------------------------------------------------------------------------
// Kernel 1: per-sample fused hash-encode + base MLP + SH + head MLP.
// Writes float4(s = sigma*(te-ts), r, g, b) per sample.
// ---------------------------------------------------------------------------
__global__ __launch_bounds__(256) void rf_sample(
    const float* __restrict__ t_starts, const float* __restrict__ t_ends,
    const float* __restrict__ rays_o,   const float* __restrict__ rays_d,
    const int*   __restrict__ ray_indices,
    const float* __restrict__ tables,
    const float* __restrict__ bw0,  // [32,64]
    const float* __restrict__ bw1,  // [64,16]
    const float* __restrict__ hw0,  // [31,64]
    const float* __restrict__ hw1,  // [64,64]
    const float* __restrict__ hw2,  // [64,3]
    const float* __restrict__ aabb,
    float4* __restrict__ srgb, int n, ResParams rp)
{
    int i = blockIdx.x * 256 + threadIdx.x;
    if (i >= n) return;

    const int   ri = ray_indices[i];
    const float ts = t_starts[i], te = t_ends[i];
    const float tmid = 0.5f * (ts + te);

    const float ox = rays_o[ri * 3 + 0], oy = rays_o[ri * 3 + 1], oz = rays_o[ri * 3 + 2];
    const float dx = rays_d[ri * 3 + 0], dy = rays_d[ri * 3 + 1], dz = rays_d[ri * 3 + 2];

    const float a0 = aabb[0], a1 = aabb[1], a2 = aabb[2];
    const float b0 = aabb[3], b1 = aabb[4], b2 = aabb[5];

    const float px = ox + dx * tmid, py = oy + dy * tmid, pz = oz + dz * tmid;
    const float xn0 = (px - a0) / (b0 - a0 + 1e-5f);
    const float xn1 = (py - a1) / (b1 - a1 + 1e-5f);
    const float xn2 = (pz - a2) / (b2 - a2 + 1e-5f);

    const bool sel = (xn0 > 0.f) && (xn0 < 1.f) && (xn1 > 0.f) && (xn1 < 1.f)
                  && (xn2 > 0.f) && (xn2 < 1.f);

    const float x0 = fminf(fmaxf(xn0, 0.f), 1.f);
    const float x1 = fminf(fmaxf(xn1, 0.f), 1.f);
    const float x2 = fminf(fmaxf(xn2, 0.f), 1.f);

    // ---- multi-resolution hash encoding -> enc[32] ----
    float enc[2 * NLEV];
    #pragma unroll
    for (int l = 0; l < NLEV; ++l) {
        const float resf = rp.resf[l];
        const float* __restrict__ tab = tables + (size_t)l * (size_t)(TBL * 2u);
        const float p0 = x0 * resf, p1 = x1 * resf, p2 = x2 * resf;
        const float fl0 = floorf(p0), fl1 = floorf(p1), fl2 = floorf(p2);
        const float f0 = p0 - fl0, f1 = p1 - fl1, f2 = p2 - fl2;
        const unsigned i0 = (unsigned)fl0, i1 = (unsigned)fl1, i2 = (unsigned)fl2;
        const unsigned hx0 = i0,                   hx1 = i0 + 1u;
        const unsigned hy0 = i1 * 2654435761u,     hy1 = hy0 + 2654435761u;
        const unsigned hz0 = i2 * 805459861u,      hz1 = hz0 + 805459861u;
        const float g0 = 1.f - f0, g1 = 1.f - f1, g2 = 1.f - f2;
        float e0 = 0.f, e1 = 0.f;
        #pragma unroll
        for (int c = 0; c < 8; ++c) {          // corner bits: 4=x, 2=y, 1=z
            unsigned h = (((c & 4) ? hx1 : hx0) ^ ((c & 2) ? hy1 : hy0)
                        ^ ((c & 1) ? hz1 : hz0)) & TMASK;
            const float w = (((c & 4) ? f0 : g0) * ((c & 2) ? f1 : g1))
                          * ((c & 1) ? f2 : g2);
            const float2 tv = *(const float2*)(tab + (size_t)h * 2u);
            e0 = fmaf(tv.x, w, e0);
            e1 = fmaf(tv.y, w, e1);
        }
        enc[2 * l]     = e0;
        enc[2 * l + 1] = e1;
    }

    // ---- base MLP: relu(enc @ bw0) @ bw1 -> h[16] ----
    float hid[64];
    #pragma unroll
    for (int j = 0; j < 64; ++j) hid[j] = 0.f;
    #pragma unroll
    for (int k = 0; k < 32; ++k) {
        const float a = enc[k];
        #pragma unroll
        for (int j = 0; j < 64; ++j) hid[j] = fmaf(a, bw0[k * 64 + j], hid[j]);
    }
    float h[16];
    #pragma unroll
    for (int j = 0; j < 16; ++j) h[j] = 0.f;
    #pragma unroll
    for (int k = 0; k < 64; ++k) {
        const float a = fmaxf(hid[k], 0.f);
        #pragma unroll
        for (int j = 0; j < 16; ++j) h[j] = fmaf(a, bw1[k * 16 + j], h[j]);
    }

    const float sigma = sel ? __expf(h[0] - 1.0f) : 0.f;

    // ---- spherical harmonics deg 4 on t_dirs ----
    const float x = dx, y = dy, z = dz;
    const float x2v = x * x, y2v = y * y, z2v = z * z;
    const float xy = x * y, yz = y * z, xz = x * z;
    float sh[16];
    sh[0]  = 0.28209479177387814f;
    sh[1]  = -0.48860251190291987f * y;
    sh[2]  = 0.48860251190291987f * z;
    sh[3]  = -0.48860251190291987f * x;
    sh[4]  = 1.0925484305920792f * xy;
    sh[5]  = -1.0925484305920792f * yz;
    sh[6]  = 0.94617469575756f * z2v - 0.31539156525252005f;
    sh[7]  = -1.0925484305920792f * xz;
    sh[8]  = 0.5462742152960396f * (x2v - y2v);
    sh[9]  = -0.5900435899266435f * y * (3.f * x2v - y2v);
    sh[10] = 2.890611442640554f * xy * z;
    sh[11] = -0.4570457994644658f * y * (4.f * z2v - x2v - y2v);
    sh[12] = 0.3731763325901154f * z * (2.f * z2v - 3.f * x2v - 3.f * y2v);
    sh[13] = -0.4570457994644658f * x * (4.f * z2v - x2v - y2v);
    sh[14] = 1.445305721320277f * z * (x2v - y2v);
    sh[15] = -0.5900435899266435f * x * (x2v - 3.f * y2v);

    // ---- head MLP: sigmoid(relu(relu(hh @ hw0) @ hw1) @ hw2) ----
    float acc2[64];
    #pragma unroll
    for (int j = 0; j < 64; ++j) acc2[j] = 0.f;
    #pragma unroll
    for (int k = 0; k < 16; ++k) {
        const float a = sh[k];
        #pragma unroll
        for (int j = 0; j < 64; ++j) acc2[j] = fmaf(a, hw0[k * 64 + j], acc2[j]);
    }
    #pragma unroll
    for (int k = 0; k < 15; ++k) {
        const float a = h[k + 1];   // embedding
        #pragma unroll
        for (int j = 0; j < 64; ++j) acc2[j] = fmaf(a, hw0[(16 + k) * 64 + j], acc2[j]);
    }

    float acc3[64];
    #pragma unroll
    for (int j = 0; j < 64; ++j) acc3[j] = 0.f;
    #pragma unroll
    for (int k = 0; k < 64; ++k) {
        const float a = fmaxf(acc2[k], 0.f);
        #pragma unroll
        for (int j = 0; j < 64; ++j) acc3[j] = fmaf(a, hw1[k * 64 + j], acc3[j]);
    }

    float cr = 0.f, cg = 0.f, cb = 0.f;
    #pragma unroll
    for (int k = 0; k < 64; ++k) {
        const float a = fmaxf(acc3[k], 0.f);
        cr = fmaf(a, hw2[k * 3 + 0], cr);
        cg = fmaf(a, hw2[k * 3 + 1], cg);
        cb = fmaf(a, hw2[k * 3 + 2], cb);
    }
    cr = sigmoidf(cr); cg = sigmoidf(cg); cb = sigmoidf(cb);

    const float s = sigma * (te - ts);
    srgb[i] = make_float4(s, cr, cg, cb);
}

// ---------------------------------------------------------------------------
// Kernel 2: per-ray sequential volume rendering (ray_indices sorted).
// ---------------------------------------------------------------------------
__global__ __launch_bounds__(256) void rf_render(
    const float* __restrict__ t_starts, const float* __restrict__ t_ends,
    const int*   __restrict__ ray_indices,
    const float4* __restrict__ srgb,
    float* __restrict__ out, int n_samples, int n_rays)
{
    const int r = blockIdx.x * 256 + threadIdx.x;
    if (r >= n_rays) return;

    // first index with ray_indices[idx] >= r
    int lo = 0, hi = n_samples;
    while (lo < hi) { int mid = (lo + hi) >> 1; if (ray_indices[mid] < r) lo = mid + 1; else hi = mid; }
    const int start = lo;
    hi = n_samples;
    while (lo < hi) { int mid = (lo + hi) >> 1; if (ray_indices[mid] <= r) lo = mid + 1; else hi = mid; }
    const int end = lo;

    float trans = 1.f;
    float cr = 0.f, cg = 0.f, cb = 0.f, op = 0.f, dw = 0.f;
    for (int j = start; j < end; ++j) {
        const float4 v = srgb[j];
        const float em = __expf(-v.x);
        const float w = trans * (1.f - em);
        cr += w * v.y; cg += w * v.z; cb += w * v.w;
        op += w;
        const float tm = 0.5f * (t_starts[j] + t_ends[j]);
        dw += w * tm;
        trans *= em;
    }
    out[r * 3 + 0] = cr;
    out[r * 3 + 1] = cg;
    out[r * 3 + 2] = cb;
    out[n_rays * 3 + r] = op;
    out[n_rays * 4 + r] = dw / fmaxf(op, 1.1920929e-7f);
}

// ---------------------------------------------------------------------------
extern "C" void kernel_launch(void* const* d_in, const int* in_sizes, int n_in,
                              void* d_out, int out_size, void* d_ws, size_t ws_size,
                              hipStream_t stream)
{
    const float* t_starts    = (const float*)d_in[0];
    const float* t_ends      = (const float*)d_in[1];
    const float* rays_o      = (const float*)d_in[2];
    const float* rays_d      = (const float*)d_in[3];
    const int*   ray_indices = (const int*)  d_in[4];
    const float* tables      = (const float*)d_in[5];
    const float* bw0         = (const float*)d_in[6];
    const float* bw1         = (const float*)d_in[7];
    const float* hw0         = (const float*)d_in[8];
    const float* hw1         = (const float*)d_in[9];
    const float* hw2         = (const float*)d_in[10];
    const float* aabb        = (const float*)d_in[11];

    const int n      = in_sizes[0];
    const int n_rays = in_sizes[2] / 3;

    float*  out  = (float*)d_out;
    float4* srgb = (float4*)d_ws;   // n * 16 bytes

    // Replicate numpy: RES = floor(BASE * SCALE**arange(L)) in float64.
    ResParams rp;
    const double scale = exp((log(4096.0) - log(16.0)) / 15.0);
    for (int l = 0; l < NLEV; ++l)
        rp.resf[l] = (float)floor(16.0 * pow(scale, (double)l));

    rf_sample<<<(n + 255) / 256, 256, 0, stream>>>(
        t_starts, t_ends, rays_o, rays_d, ray_indices, tables,
        bw0, bw1, hw0, hw1, hw2, aabb, srgb, n, rp);

    rf_render<<<(n_rays + 255) / 256, 256, 0, stream>>>(
        t_starts, t_ends, ray_indices, srgb, out, n, n_rays);
}

// Round 2
// 436.934 us; speedup vs baseline: 2.0414x; 2.0414x over previous
//
#include <hip/hip_runtime.h>
#include <math.h>

#define NLEV 16
#define TBL  (1u << 19)
#define TMASK (TBL - 1u)

typedef _Float16 half8  __attribute__((ext_vector_type(8)));
typedef float    floatx4 __attribute__((ext_vector_type(4)));

struct ResParams { float resf[NLEV]; };

__device__ __forceinline__ float sigmoidf(float x) {
    return 1.0f / (1.0f + __expf(-x));
}

// XOR-swizzled index into a [rows][64] f16 buffer stored with stride 64.
// 16-byte blocks within a row are permuted by row&7 -> conflict-free b128
// reads for the MFMA A/B fragment pattern (addr = row*128 + ((blk^(row&7))*16)).
__device__ __forceinline__ int swz64(int row, int col) {
    return row * 64 + ((((col >> 3) ^ (row & 7)) << 3) | (col & 7));
}
__device__ __forceinline__ int swz64_blk(int row, int colblk8) {
    // colblk8 = col/8 (0..7); returns f16 index of the 8-elem block start
    return row * 64 + (((colblk8 ^ (row & 7)) << 3));
}

// ---------------------------------------------------------------------------
// Kernel 1: hash encoding only. High occupancy for random-gather latency.
// Writes enc*1024 as f16 [n][32] (row = 64 B, coalesced dwordx4 stores).
// ---------------------------------------------------------------------------
__global__ __launch_bounds__(256) void k_hash(
    const float* __restrict__ t_starts, const float* __restrict__ t_ends,
    const float* __restrict__ rays_o,   const float* __restrict__ rays_d,
    const int*   __restrict__ ray_indices,
    const float* __restrict__ tables,
    const float* __restrict__ aabb,
    _Float16* __restrict__ encG, int n, ResParams rp)
{
    int i = blockIdx.x * 256 + threadIdx.x;
    if (i >= n) return;

    const int   ri = ray_indices[i];
    const float ts = t_starts[i], te = t_ends[i];
    const float tmid = 0.5f * (ts + te);

    const float ox = rays_o[ri * 3 + 0], oy = rays_o[ri * 3 + 1], oz = rays_o[ri * 3 + 2];
    const float dx = rays_d[ri * 3 + 0], dy = rays_d[ri * 3 + 1], dz = rays_d[ri * 3 + 2];

    const float a0 = aabb[0], a1 = aabb[1], a2 = aabb[2];
    const float b0 = aabb[3], b1 = aabb[4], b2 = aabb[5];

    const float px = ox + dx * tmid, py = oy + dy * tmid, pz = oz + dz * tmid;
    const float xn0 = (px - a0) / (b0 - a0 + 1e-5f);
    const float xn1 = (py - a1) / (b1 - a1 + 1e-5f);
    const float xn2 = (pz - a2) / (b2 - a2 + 1e-5f);

    const float x0 = fminf(fmaxf(xn0, 0.f), 1.f);
    const float x1 = fminf(fmaxf(xn1, 0.f), 1.f);
    const float x2 = fminf(fmaxf(xn2, 0.f), 1.f);

    union { _Float16 h[32]; uint4 q[4]; } ev;

    #pragma unroll
    for (int l = 0; l < NLEV; ++l) {
        const float resf = rp.resf[l];
        const float* __restrict__ tab = tables + (size_t)l * (size_t)(TBL * 2u);
        const float p0 = x0 * resf, p1 = x1 * resf, p2 = x2 * resf;
        const float fl0 = floorf(p0), fl1 = floorf(p1), fl2 = floorf(p2);
        const float f0 = p0 - fl0, f1 = p1 - fl1, f2 = p2 - fl2;
        const unsigned i0 = (unsigned)fl0, i1 = (unsigned)fl1, i2 = (unsigned)fl2;
        const unsigned hx0 = i0,               hx1 = i0 + 1u;
        const unsigned hy0 = i1 * 2654435761u, hy1 = hy0 + 2654435761u;
        const unsigned hz0 = i2 * 805459861u,  hz1 = hz0 + 805459861u;
        const float g0 = 1.f - f0, g1 = 1.f - f1, g2 = 1.f - f2;
        float e0 = 0.f, e1 = 0.f;
        #pragma unroll
        for (int c = 0; c < 8; ++c) {       // corner bits: 4=x, 2=y, 1=z
            unsigned h = (((c & 4) ? hx1 : hx0) ^ ((c & 2) ? hy1 : hy0)
                        ^ ((c & 1) ? hz1 : hz0)) & TMASK;
            const float w = (((c & 4) ? f0 : g0) * ((c & 2) ? f1 : g1))
                          * ((c & 1) ? f2 : g2);
            const float2 tv = *(const float2*)(tab + (size_t)h * 2u);
            e0 = fmaf(tv.x, w, e0);
            e1 = fmaf(tv.y, w, e1);
        }
        // *1024 keeps tiny encodings in f16-normal range; undone after GEMM2.
        ev.h[2 * l]     = (_Float16)(e0 * 1024.f);
        ev.h[2 * l + 1] = (_Float16)(e1 * 1024.f);
    }

    uint4* dst = (uint4*)(encG + (size_t)i * 32);
    dst[0] = ev.q[0]; dst[1] = ev.q[1]; dst[2] = ev.q[2]; dst[3] = ev.q[3];
}

// ---------------------------------------------------------------------------
// Kernel 2: fused MLP via MFMA f16. Block = 256 samples = 4 waves; each wave
// owns 64 rows -> only one barrier (after coop LDS staging).
// MFMA 16x16x32 f16 layouts (gfx950):
//   A[m=lane&15][k=quad*8+j], B[k=quad*8+j][n=lane&15],
//   D: row=quad*4+reg, col=lane&15.
// ---------------------------------------------------------------------------
__global__ __launch_bounds__(256) void k_mlp(
    const float* __restrict__ t_starts, const float* __restrict__ t_ends,
    const float* __restrict__ rays_o,   const float* __restrict__ rays_d,
    const int*   __restrict__ ray_indices,
    const float* __restrict__ bw0,  // [32,64]
    const float* __restrict__ bw1,  // [64,16]
    const float* __restrict__ hw0,  // [31,64]
    const float* __restrict__ hw1,  // [64,64]
    const float* __restrict__ hw2,  // [64,3]
    const float* __restrict__ aabb,
    const _Float16* __restrict__ encG,
    float4* __restrict__ srgb, int n)
{
    __shared__ _Float16 sHID[256 * 64];   // 32 KB, swizzled; hid then a2
    __shared__ _Float16 sSH [256 * 16];   // 8 KB
    __shared__ _Float16 sHB [256 * 16];   // 8 KB: h[1..15] + zero pad col 15
    __shared__ _Float16 sW0T[64 * 40];    // 5 KB: hw0^T, K padded 31->32
    __shared__ _Float16 sW1T[64 * 64];    // 8 KB, swizzled: hw1^T
    __shared__ float    sHW2[192];        // hw2
    __shared__ float    sDT [256];        // sel ? (te-ts) : 0

    const int t     = threadIdx.x;
    const int gbase = blockIdx.x * 256;

    // ---- cooperative staging ----
    {
        const int s  = gbase + t;           // n % 256 == 0 for this problem
        const int ri = ray_indices[s];
        const float ts = t_starts[s], te = t_ends[s];
        const float tmid = 0.5f * (ts + te);
        const float ox = rays_o[ri*3+0], oy = rays_o[ri*3+1], oz = rays_o[ri*3+2];
        const float dx = rays_d[ri*3+0], dy = rays_d[ri*3+1], dz = rays_d[ri*3+2];
        const float a0 = aabb[0], a1 = aabb[1], a2c = aabb[2];
        const float b0 = aabb[3], b1 = aabb[4], b2c = aabb[5];
        const float xn0 = (ox + dx*tmid - a0) / (b0 - a0 + 1e-5f);
        const float xn1 = (oy + dy*tmid - a1) / (b1 - a1 + 1e-5f);
        const float xn2 = (oz + dz*tmid - a2c) / (b2c - a2c + 1e-5f);
        const bool sel = (xn0 > 0.f) && (xn0 < 1.f) && (xn1 > 0.f) && (xn1 < 1.f)
                      && (xn2 > 0.f) && (xn2 < 1.f);
        sDT[t] = sel ? (te - ts) : 0.f;

        const float x = dx, y = dy, z = dz;
        const float x2 = x*x, y2 = y*y, z2 = z*z;
        const float xy = x*y, yz = y*z, xz = x*z;
        float shv[16];
        shv[0]  = 0.28209479177387814f;
        shv[1]  = -0.48860251190291987f * y;
        shv[2]  = 0.48860251190291987f * z;
        shv[3]  = -0.48860251190291987f * x;
        shv[4]  = 1.0925484305920792f * xy;
        shv[5]  = -1.0925484305920792f * yz;
        shv[6]  = 0.94617469575756f * z2 - 0.31539156525252005f;
        shv[7]  = -1.0925484305920792f * xz;
        shv[8]  = 0.5462742152960396f * (x2 - y2);
        shv[9]  = -0.5900435899266435f * y * (3.f*x2 - y2);
        shv[10] = 2.890611442640554f * xy * z;
        shv[11] = -0.4570457994644658f * y * (4.f*z2 - x2 - y2);
        shv[12] = 0.3731763325901154f * z * (2.f*z2 - 3.f*x2 - 3.f*y2);
        shv[13] = -0.4570457994644658f * x * (4.f*z2 - x2 - y2);
        shv[14] = 1.445305721320277f * z * (x2 - y2);
        shv[15] = -0.5900435899266435f * x * (x2 - 3.f*y2);
        #pragma unroll
        for (int k = 0; k < 16; ++k) sSH[t*16 + k] = (_Float16)shv[k];
    }
    {
        const int nidx = t & 63, g = t >> 6;
        #pragma unroll
        for (int i2 = 0; i2 < 8; ++i2) {           // hw0^T with zero pad k=31
            const int k = g*8 + i2;
            const float v = (k < 31) ? hw0[k*64 + nidx] : 0.f;
            sW0T[nidx*40 + k] = (_Float16)v;
        }
        #pragma unroll
        for (int i2 = 0; i2 < 16; ++i2) {          // hw1^T, swizzled
            const int k = g*16 + i2;
            sW1T[swz64(nidx, k)] = (_Float16)hw1[k*64 + nidx];
        }
        if (t < 192) sHW2[t] = hw2[t];
    }

    // per-lane B-fragment preload (from global, once)
    const int lane = t & 63, w = t >> 6;
    const int nn = lane & 15, quad = lane >> 4;
    half8 B1[4];                                   // bw0: K=32, N=64 (4 tiles)
    #pragma unroll
    for (int ct = 0; ct < 4; ++ct)
        #pragma unroll
        for (int j = 0; j < 8; ++j)
            B1[ct][j] = (_Float16)bw0[(quad*8 + j)*64 + ct*16 + nn];
    half8 B2[2];                                   // bw1: K=64, N=16
    #pragma unroll
    for (int ks = 0; ks < 2; ++ks)
        #pragma unroll
        for (int j = 0; j < 8; ++j)
            B2[ks][j] = (_Float16)bw1[(ks*32 + quad*8 + j)*16 + nn];

    __syncthreads();   // the only barrier

    const int rbase = w * 64;
    float sigv[16];    // s = sigma*(te-ts)*sel per (rt,reg); valid on nn==0 lanes

    // ---- GEMM1 (enc@bw0, relu) + GEMM2 (@bw1 -> h, sigma) ----
    #pragma unroll
    for (int rt = 0; rt < 4; ++rt) {
        const int mrow = rbase + rt*16 + nn;       // A-row (frag reads)
        const int drow = rbase + rt*16 + quad*4;   // D-row base (epilogues)

        half8 a1 = *(const half8*)(encG + (size_t)(gbase + mrow)*32 + quad*8);
        #pragma unroll
        for (int ct = 0; ct < 4; ++ct) {
            floatx4 acc = {0.f, 0.f, 0.f, 0.f};
            acc = __builtin_amdgcn_mfma_f32_16x16x32_f16(a1, B1[ct], acc, 0, 0, 0);
            #pragma unroll
            for (int r2 = 0; r2 < 4; ++r2)
                sHID[swz64(drow + r2, ct*16 + nn)] = (_Float16)fmaxf(acc[r2], 0.f);
        }

        half8 a20 = *(const half8*)&sHID[swz64_blk(mrow, 0*4 + quad)];
        half8 a21 = *(const half8*)&sHID[swz64_blk(mrow, 1*4 + quad)];
        floatx4 acc = {0.f, 0.f, 0.f, 0.f};
        acc = __builtin_amdgcn_mfma_f32_16x16x32_f16(a20, B2[0], acc, 0, 0, 0);
        acc = __builtin_amdgcn_mfma_f32_16x16x32_f16(a21, B2[1], acc, 0, 0, 0);
        #pragma unroll
        for (int r2 = 0; r2 < 4; ++r2) {
            const float h = acc[r2] * (1.f / 1024.f);   // undo enc scale
            if (nn == 0) {
                sigv[rt*4 + r2] = __expf(h - 1.f) * sDT[drow + r2];
                sHB[(drow + r2)*16 + 15] = (_Float16)0.f;   // K-pad column
            } else {
                sHB[(drow + r2)*16 + (nn - 1)] = (_Float16)h;
            }
        }
    }

    // ---- GEMM3 (hh@hw0, relu) + GEMM4 (@hw1, relu) + head_w2 reduction ----
    #pragma unroll
    for (int rt = 0; rt < 4; ++rt) {
        const int mrow = rbase + rt*16 + nn;
        const int drow = rbase + rt*16 + quad*4;

        // hh A-frag: quads 0,1 <- SH (k 0..15); quads 2,3 <- h[1..15]+pad
        half8 shf = *(const half8*)&sSH[mrow*16 + (quad & 1)*8];
        half8 hbf = *(const half8*)&sHB[mrow*16 + (quad & 1)*8];
        half8 a3f = (quad < 2) ? shf : hbf;

        #pragma unroll
        for (int ct = 0; ct < 4; ++ct) {
            half8 bf = *(const half8*)&sW0T[(ct*16 + nn)*40 + quad*8];
            floatx4 acc = {0.f, 0.f, 0.f, 0.f};
            acc = __builtin_amdgcn_mfma_f32_16x16x32_f16(a3f, bf, acc, 0, 0, 0);
            #pragma unroll
            for (int r2 = 0; r2 < 4; ++r2)
                sHID[swz64(drow + r2, ct*16 + nn)] = (_Float16)fmaxf(acc[r2], 0.f);
        }

        float pr[4][3];
        #pragma unroll
        for (int r2 = 0; r2 < 4; ++r2) { pr[r2][0] = 0.f; pr[r2][1] = 0.f; pr[r2][2] = 0.f; }

        #pragma unroll
        for (int ct = 0; ct < 4; ++ct) {
            floatx4 acc = {0.f, 0.f, 0.f, 0.f};
            #pragma unroll
            for (int ks = 0; ks < 2; ++ks) {
                half8 af = *(const half8*)&sHID[swz64_blk(mrow, ks*4 + quad)];
                half8 bf = *(const half8*)&sW1T[swz64_blk(ct*16 + nn, ks*4 + quad)];
                acc = __builtin_amdgcn_mfma_f32_16x16x32_f16(af, bf, acc, 0, 0, 0);
            }
            const float w0c = sHW2[(ct*16 + nn)*3 + 0];
            const float w1c = sHW2[(ct*16 + nn)*3 + 1];
            const float w2c = sHW2[(ct*16 + nn)*3 + 2];
            #pragma unroll
            for (int r2 = 0; r2 < 4; ++r2) {
                const float a3v = fmaxf(acc[r2], 0.f);
                pr[r2][0] = fmaf(a3v, w0c, pr[r2][0]);
                pr[r2][1] = fmaf(a3v, w1c, pr[r2][1]);
                pr[r2][2] = fmaf(a3v, w2c, pr[r2][2]);
            }
        }
        // reduce over the 16 n-lanes of each quad
        #pragma unroll
        for (int off = 1; off < 16; off <<= 1)
            #pragma unroll
            for (int r2 = 0; r2 < 4; ++r2) {
                pr[r2][0] += __shfl_xor(pr[r2][0], off, 64);
                pr[r2][1] += __shfl_xor(pr[r2][1], off, 64);
                pr[r2][2] += __shfl_xor(pr[r2][2], off, 64);
            }
        if (nn == 0) {
            #pragma unroll
            for (int r2 = 0; r2 < 4; ++r2) {
                float4 o;
                o.x = sigv[rt*4 + r2];
                o.y = sigmoidf(pr[r2][0]);
                o.z = sigmoidf(pr[r2][1]);
                o.w = sigmoidf(pr[r2][2]);
                srgb[gbase + drow + r2] = o;
            }
        }
    }
}

// ---------------------------------------------------------------------------
// Kernel 3: wave-per-ray compositing with shfl prefix scan.
// ---------------------------------------------------------------------------
__global__ __launch_bounds__(256) void k_render(
    const float* __restrict__ t_starts, const float* __restrict__ t_ends,
    const int*   __restrict__ ray_indices,
    const float4* __restrict__ srgb,
    float* __restrict__ out, int n_samples, int n_rays)
{
    const int wid  = (blockIdx.x * 256 + threadIdx.x) >> 6;
    const int lane = threadIdx.x & 63;
    if (wid >= n_rays) return;
    const int r = wid;

    int lo = 0, hi = n_samples;
    while (lo < hi) { int mid = (lo + hi) >> 1; if (ray_indices[mid] <  r) lo = mid + 1; else hi = mid; }
    const int start = lo;
    hi = n_samples;
    while (lo < hi) { int mid = (lo + hi) >> 1; if (ray_indices[mid] <= r) lo = mid + 1; else hi = mid; }
    const int end = lo;

    float S = 0.f, cr = 0.f, cg = 0.f, cb = 0.f, op = 0.f, dw = 0.f;
    for (int j0 = start; j0 < end; j0 += 64) {
        const int j = j0 + lane;
        float s = 0.f, R = 0.f, G = 0.f, B = 0.f, tm = 0.f;
        if (j < end) {
            const float4 v = srgb[j];
            s = v.x; R = v.y; G = v.z; B = v.w;
            tm = 0.5f * (t_starts[j] + t_ends[j]);
        }
        float incl = s;
        #pragma unroll
        for (int off = 1; off < 64; off <<= 1) {
            const float tv = __shfl_up(incl, off, 64);
            if (lane >= off) incl += tv;
        }
        const float excl  = incl - s;
        const float trans = __expf(-(S + excl));
        const float alpha = 1.f - __expf(-s);
        const float wgt   = trans * alpha;
        cr += wgt * R; cg += wgt * G; cb += wgt * B;
        op += wgt;     dw += wgt * tm;
        S += __shfl(incl, 63, 64);
    }
    #pragma unroll
    for (int off = 1; off < 64; off <<= 1) {
        cr += __shfl_xor(cr, off, 64);
        cg += __shfl_xor(cg, off, 64);
        cb += __shfl_xor(cb, off, 64);
        op += __shfl_xor(op, off, 64);
        dw += __shfl_xor(dw, off, 64);
    }
    if (lane == 0) {
        out[r*3 + 0] = cr;
        out[r*3 + 1] = cg;
        out[r*3 + 2] = cb;
        out[n_rays*3 + r] = op;
        out[n_rays*4 + r] = dw / fmaxf(op, 1.1920929e-7f);
    }
}

// ---------------------------------------------------------------------------
extern "C" void kernel_launch(void* const* d_in, const int* in_sizes, int n_in,
                              void* d_out, int out_size, void* d_ws, size_t ws_size,
                              hipStream_t stream)
{
    const float* t_starts    = (const float*)d_in[0];
    const float* t_ends      = (const float*)d_in[1];
    const float* rays_o      = (const float*)d_in[2];
    const float* rays_d      = (const float*)d_in[3];
    const int*   ray_indices = (const int*)  d_in[4];
    const float* tables      = (const float*)d_in[5];
    const float* bw0         = (const float*)d_in[6];
    const float* bw1         = (const float*)d_in[7];
    const float* hw0         = (const float*)d_in[8];
    const float* hw1         = (const float*)d_in[9];
    const float* hw2         = (const float*)d_in[10];
    const float* aabb        = (const float*)d_in[11];

    const int n      = in_sizes[0];        // 524288 (divisible by 256)
    const int n_rays = in_sizes[2] / 3;    // 8192

    float*     out  = (float*)d_out;
    _Float16*  encG = (_Float16*)d_ws;                            // n*64 B
    float4*    srgb = (float4*)((char*)d_ws + (size_t)n * 64);    // n*16 B

    ResParams rp;
    const double scale = exp((log(4096.0) - log(16.0)) / 15.0);
    for (int l = 0; l < NLEV; ++l)
        rp.resf[l] = (float)floor(16.0 * pow(scale, (double)l));

    const int nblk = (n + 255) / 256;
    k_hash<<<nblk, 256, 0, stream>>>(t_starts, t_ends, rays_o, rays_d,
                                     ray_indices, tables, aabb, encG, n, rp);
    k_mlp<<<nblk, 256, 0, stream>>>(t_starts, t_ends, rays_o, rays_d,
                                    ray_indices, bw0, bw1, hw0, hw1, hw2,
                                    aabb, encG, srgb, n);
    k_render<<<(n_rays * 64 + 255) / 256, 256, 0, stream>>>(
        t_starts, t_ends, ray_indices, srgb, out, n, n_rays);
}